// Round 8
// baseline (526.021 us; speedup 1.0000x reference)
//
#include <hip/hip_runtime.h>
#include <hip/hip_bf16.h>

#define NB 8
#define LSEQ 2048
#define HH 8
#define DD 32
#define EE 256
#define NE 32
#define QT 16      // queries per block (one MFMA tile of rows)
#define NTH 1024
#define KW 128     // keys per wave
#define NTILE 8    // KW / 16
#define SMS 2050   // smean row stride (words); 2-way bank alias on RMW (minimal)

// zinv kernel geometry
#define ZQT 64     // queries per z-block
#define ZNT 512    // threads
#define ZKW 256    // keys per wave (8 waves x 256 = 2048)
#define ZNTILE 16  // ZKW / 16

typedef __attribute__((ext_vector_type(8))) short short8;
typedef __attribute__((ext_vector_type(4))) float f32x4;

// ---------------------------------------------------------------------------
// K1: per-head projection -> 3-way bf16 split (hi/mid/lo ~ 24 mantissa bits).
// Q pass folds softmax temperature AND 1/ln2: scale = 1/(16*ln2) -> exp2.
// ---------------------------------------------------------------------------
__global__ __launch_bounds__(256) void proj_kernel(const float* __restrict__ x,
                                                   const float* __restrict__ W,
                                                   float scale,
                                                   __hip_bfloat16* __restrict__ o1,
                                                   __hip_bfloat16* __restrict__ o2,
                                                   __hip_bfloat16* __restrict__ o3) {
  const int b = blockIdx.x;  // n*L + l
  __shared__ float xs[EE];
  __shared__ float Ws[DD][DD + 1];
  const int t = threadIdx.x;
  xs[t] = x[(size_t)b * EE + t];
  for (int i = t; i < DD * DD; i += 256) Ws[i / DD][i % DD] = W[i];
  __syncthreads();
  const int h = t / DD, e = t % DD;
  float acc = 0.f;
#pragma unroll
  for (int d = 0; d < DD; ++d) acc = fmaf(xs[h * DD + d], Ws[e][d], acc);
  acc *= scale;
  const int n = b / LSEQ, l = b % LSEQ;
  const size_t oi = (((size_t)n * HH + h) * LSEQ + l) * DD + e;
  __hip_bfloat16 p1 = __float2bfloat16(acc);
  float r1 = acc - __bfloat162float(p1);
  __hip_bfloat16 p2 = __float2bfloat16(r1);
  float r2 = r1 - __bfloat162float(p2);
  __hip_bfloat16 p3 = __float2bfloat16(r2);
  o1[oi] = p1;
  o2[oi] = p2;
  o3[oi] = p3;
}

// ---------------------------------------------------------------------------
// K2: Z (softmax denominator) -> inv = rcp(Z), decoupled from the main pass.
// inv is a per-(h,row) uniform scale: its rounding cannot change within-row
// ordering, so it may be computed in a different kernel / summation order.
// Block = (n, 64 queries), 512 thr. Wave w owns 256 keys and computes ALL
// four 16-query subtiles per K-load (4x K reuse). One barrier total.
// ---------------------------------------------------------------------------
__global__ __launch_bounds__(ZNT) void zinv_kernel(
    const __hip_bfloat16* __restrict__ q1, const __hip_bfloat16* __restrict__ q2,
    const __hip_bfloat16* __restrict__ q3, const __hip_bfloat16* __restrict__ k1,
    const __hip_bfloat16* __restrict__ k2, const __hip_bfloat16* __restrict__ k3,
    float* __restrict__ invp) {
  __shared__ float zlds[HH][ZQT];  // 2 KB of Z accumulators

  const int t = threadIdx.x;
  const int w = t >> 6, l = t & 63;
  const int g = l >> 4, c = l & 15;
  const int n = blockIdx.x & 7;            // 256 blocks, %8==0: bijective
  const int q0 = (blockIdx.x >> 3) * ZQT;

  ((float*)zlds)[t] = 0.f;  // ZNT == HH*ZQT
  __syncthreads();

  for (int h = 0; h < HH; ++h) {
    const size_t hb = ((size_t)n * HH + h) * LSEQ;
    // Q fragments for all 4 query-subtiles (row = qs*16 + c)
    short8 aH[4], aM[4], aL[4];
#pragma unroll
    for (int qs = 0; qs < 4; ++qs) {
      const size_t qoff = (hb + q0 + qs * 16 + c) * DD + (size_t)g * 8;
      aH[qs] = *(const short8*)(q1 + qoff);
      aM[qs] = *(const short8*)(q2 + qoff);
      aL[qs] = *(const short8*)(q3 + qoff);
    }
    float Zl[4][4];
#pragma unroll
    for (int qs = 0; qs < 4; ++qs)
#pragma unroll
      for (int r = 0; r < 4; ++r) Zl[qs][r] = 0.f;

    for (int t2 = 0; t2 < ZNTILE; ++t2) {
      const size_t koff = (hb + (size_t)w * ZKW + t2 * 16 + c) * DD + (size_t)g * 8;
      const short8 bH = *(const short8*)(k1 + koff);
      const short8 bM = *(const short8*)(k2 + koff);
      const short8 bL = *(const short8*)(k3 + koff);
#pragma unroll
      for (int qs = 0; qs < 4; ++qs) {
        f32x4 a = {0.f, 0.f, 0.f, 0.f};
        a = __builtin_amdgcn_mfma_f32_16x16x32_bf16(aH[qs], bH, a, 0, 0, 0);
        a = __builtin_amdgcn_mfma_f32_16x16x32_bf16(aH[qs], bM, a, 0, 0, 0);
        a = __builtin_amdgcn_mfma_f32_16x16x32_bf16(aM[qs], bH, a, 0, 0, 0);
        a = __builtin_amdgcn_mfma_f32_16x16x32_bf16(aH[qs], bL, a, 0, 0, 0);
        a = __builtin_amdgcn_mfma_f32_16x16x32_bf16(aL[qs], bH, a, 0, 0, 0);
        a = __builtin_amdgcn_mfma_f32_16x16x32_bf16(aM[qs], bM, a, 0, 0, 0);
#pragma unroll
        for (int r = 0; r < 4; ++r) Zl[qs][r] += exp2f(a[r]);
      }
    }
    // reduce over the 16 lanes of each c-group, then atomically into LDS
#pragma unroll
    for (int msk = 1; msk <= 8; msk <<= 1)
#pragma unroll
      for (int qs = 0; qs < 4; ++qs)
#pragma unroll
        for (int r = 0; r < 4; ++r) Zl[qs][r] += __shfl_xor(Zl[qs][r], msk);
    if (c == 0) {
#pragma unroll
      for (int qs = 0; qs < 4; ++qs)
#pragma unroll
        for (int r = 0; r < 4; ++r) atomicAdd(&zlds[h][qs * 16 + g * 4 + r], Zl[qs][r]);
    }
  }
  __syncthreads();
  const int h2 = t >> 6, qi = t & 63;
  invp[((size_t)n * HH + h2) * LSEQ + q0 + qi] = __builtin_amdgcn_rcpf(zlds[h2][qi]);
}

// ---------------------------------------------------------------------------
// K3: MFMA energy -> exp2 -> x inv (precomputed) -> RMW-accumulate mean into
// LDS -> top-32.  Head loop has NO barriers, NO shuffles, NO reductions:
// pure stream of loads/MFMA/exp/RMW, freely pipelined across heads.
// One block = (n, 16-query tile). 16 waves; wave w owns keys [w*128,(w+1)*128).
// Live regs ~40 -> fits the 64-VGPR bin the allocator forces on 1024-thr WGs.
// C fragment mapping (verified rounds 2-7): row(query)=g*4+r, col(key)=c.
// ---------------------------------------------------------------------------
__global__ __launch_bounds__(NTH) void attn_topk_kernel(
    const __hip_bfloat16* __restrict__ q1, const __hip_bfloat16* __restrict__ q2,
    const __hip_bfloat16* __restrict__ q3, const __hip_bfloat16* __restrict__ k1,
    const __hip_bfloat16* __restrict__ k2, const __hip_bfloat16* __restrict__ k3,
    const float* __restrict__ invp, int* __restrict__ out) {
  __shared__ float smean[QT * SMS];  // 131 KB mean accumulator
  __shared__ float ilds[HH][QT];     // preloaded inv values

  const int t = threadIdx.x;
  const int w = t >> 6, l = t & 63;
  const int g = l >> 4, c = l & 15;
  const int n = blockIdx.x & 7;      // 1024 blocks, %8==0: bijective
  const int q0 = (blockIdx.x >> 3) * QT;

  for (int i = t; i < QT * SMS; i += NTH) smean[i] = 0.f;
  if (t < HH * QT) {
    const int h = t >> 4, qi = t & 15;
    ilds[h][qi] = invp[((size_t)n * HH + h) * LSEQ + q0 + qi];
  }
  float* macc = &smean[(g * 4) * SMS + w * KW + c];
  __syncthreads();

  for (int h = 0; h < HH; ++h) {
    const size_t hb = ((size_t)n * HH + h) * LSEQ;
    const size_t qoff = (hb + q0 + c) * DD + (size_t)g * 8;
    const short8 aH = *(const short8*)(q1 + qoff);
    const short8 aM = *(const short8*)(q2 + qoff);
    const short8 aL = *(const short8*)(q3 + qoff);
    float iv[4];
#pragma unroll
    for (int r = 0; r < 4; ++r) iv[r] = ilds[h][g * 4 + r];

#pragma unroll
    for (int t2 = 0; t2 < NTILE; ++t2) {
      const size_t koff = (hb + (size_t)w * KW + t2 * 16 + c) * DD + (size_t)g * 8;
      const short8 bH = *(const short8*)(k1 + koff);
      const short8 bM = *(const short8*)(k2 + koff);
      const short8 bL = *(const short8*)(k3 + koff);
      f32x4 a = {0.f, 0.f, 0.f, 0.f};
      a = __builtin_amdgcn_mfma_f32_16x16x32_bf16(aH, bH, a, 0, 0, 0);
      a = __builtin_amdgcn_mfma_f32_16x16x32_bf16(aH, bM, a, 0, 0, 0);
      a = __builtin_amdgcn_mfma_f32_16x16x32_bf16(aM, bH, a, 0, 0, 0);
      a = __builtin_amdgcn_mfma_f32_16x16x32_bf16(aH, bL, a, 0, 0, 0);
      a = __builtin_amdgcn_mfma_f32_16x16x32_bf16(aL, bH, a, 0, 0, 0);
      a = __builtin_amdgcn_mfma_f32_16x16x32_bf16(aM, bM, a, 0, 0, 0);
#pragma unroll
      for (int r = 0; r < 4; ++r) {
        float* p = macc + r * SMS + t2 * 16;
        *p = fmaf(exp2f(a[r]), iv[r], *p);
      }
    }
  }
  __syncthreads();

  // --- top-32: wave w owns row w (query q0+w); k = j*64 + l ---
  float* row = &smean[w * SMS];
  float vals[32];
  float v1 = -1e30f, v2 = -1e30f;
  int i1 = 1 << 30, i2 = 1 << 30;
#pragma unroll
  for (int j = 0; j < 32; ++j) {
    float v = row[j * 64 + l];
    vals[j] = v;
    const int k = j * 64 + l;
    if (v > v1) { v2 = v1; i2 = i1; v1 = v; i1 = k; }
    else if (v > v2) { v2 = v; i2 = k; }
  }
  unsigned rem = 0u;
  int selk = 0;
#pragma unroll 1
  for (int it = 0; it < NE; ++it) {
    float bv = v1;
    int bk = i1;
#pragma unroll
    for (int off = 32; off >= 1; off >>= 1) {
      float ov = __shfl_xor(bv, off);
      int ok = __shfl_xor(bk, off);
      if (ov > bv || (ov == bv && ok < bk)) { bv = ov; bk = ok; }
    }
    if (l == it) selk = bk;
    if (i1 == bk) {  // this lane supplied the winner (k%64==l: unique owner)
      rem |= 1u << (bk >> 6);
      if (i2 != (1 << 30)) {  // promote cached second
        v1 = v2; i1 = i2;
        v2 = -1e30f; i2 = 1 << 30;
      } else {  // rare: rebuild top-2 from masked registers
        v1 = -1e30f; i1 = 1 << 30;
        v2 = -1e30f; i2 = 1 << 30;
#pragma unroll
        for (int j = 0; j < 32; ++j) {
          float v = ((rem >> j) & 1u) ? -1e30f : vals[j];
          const int k = j * 64 + l;
          if (v > v1) { v2 = v1; i2 = i1; v1 = v; i1 = k; }
          else if (v > v2) { v2 = v; i2 = k; }
        }
      }
    }
  }

  // --- rank-sort the 32 winners by index, write output ---
  int rank = 0;
#pragma unroll
  for (int j = 0; j < NE; ++j) {
    int o = __shfl(selk, j);
    rank += (o < selk) ? 1 : 0;
  }
  const int qg = q0 + w;
  if (l < NE) {
    int* o0 = out + (size_t)n * 2 * LSEQ * NE + (size_t)qg * NE;
    int* o1p = o0 + (size_t)LSEQ * NE;
    o0[l] = qg;
    o1p[rank] = selk;
  }
}

// ---------------------------------------------------------------------------
extern "C" void kernel_launch(void* const* d_in, const int* in_sizes, int n_in,
                              void* d_out, int out_size, void* d_ws, size_t ws_size,
                              hipStream_t stream) {
  const float* keys = (const float*)d_in[0];
  const float* query = (const float*)d_in[1];
  const float* Wk = (const float*)d_in[2];
  const float* Wq = (const float*)d_in[3];
  int* out = (int*)d_out;

  const size_t SPLIT = (size_t)NB * HH * LSEQ * DD;  // 4,194,304 elems
  __hip_bfloat16* qs1 = (__hip_bfloat16*)d_ws;
  __hip_bfloat16* qs2 = qs1 + SPLIT;
  __hip_bfloat16* qs3 = qs2 + SPLIT;
  __hip_bfloat16* ks1 = qs3 + SPLIT;
  __hip_bfloat16* ks2 = ks1 + SPLIT;
  __hip_bfloat16* ks3 = ks2 + SPLIT;
  float* invp = (float*)(ks3 + SPLIT);  // [NB][HH][LSEQ] f32, 512 KB

  // scale folds softmax temperature (1/16) and 1/ln2 for exp2-based softmax
  proj_kernel<<<NB * LSEQ, 256, 0, stream>>>(query, Wq, 0.0625f * 1.44269504088896340736f,
                                             qs1, qs2, qs3);
  proj_kernel<<<NB * LSEQ, 256, 0, stream>>>(keys, Wk, 1.0f, ks1, ks2, ks3);
  zinv_kernel<<<NB * (LSEQ / ZQT), ZNT, 0, stream>>>(qs1, qs2, qs3, ks1, ks2, ks3, invp);
  attn_topk_kernel<<<NB * (LSEQ / QT), NTH, 0, stream>>>(qs1, qs2, qs3, ks1, ks2, ks3, invp, out);
}